// Round 6
// baseline (704.944 us; speedup 1.0000x reference)
//
#include <hip/hip_runtime.h>

// MultiHeadSelfAttention: B=16, S=1024, D=768, H=12, DH=64, fp32 in/out.
// R5: occupancy + store-layout round.
//  - attn: no Q LDS tile (direct global B-frags), LDS 18.4KB -> 6 blocks/CU
//    co-resident (no tail); PV operands swapped -> O^T C-layout -> half4 stores.
//  - qkv: operands swapped (A=W,B=X) -> D=[dout][token]: half4 Q/K stores,
//    bias in acc-init; V^T via LDS bounce -> coalesced half8 stores.

#define NB 16
#define NS 1024
#define ND 768
#define NH 12
#define NDH 64
#define LDH 72        // LDS row stride in halves (144B)
#define QSCALE 0.18033688f   // 0.125 * log2(e)

typedef _Float16 half8 __attribute__((ext_vector_type(8)));
typedef _Float16 half4 __attribute__((ext_vector_type(4)));
typedef float floatx4 __attribute__((ext_vector_type(4)));

// ---------------------------------------------------------------------------
// Prep A: per-head W q/k/v -> fp16, transposed to [m][h][dout][din]; Wq scaled.
// ---------------------------------------------------------------------------
__global__ __launch_bounds__(256) void wqkv_prep(
    const float* __restrict__ Wq, const float* __restrict__ Wk,
    const float* __restrict__ Wv, _Float16* __restrict__ Wt)
{
    __shared__ float sh[64][65];
    const int m = blockIdx.x, h = blockIdx.y, tid = threadIdx.x;
    const float* Wsrc = (m == 0 ? Wq : (m == 1 ? Wk : Wv)) + h * 4096;
    const float scale = (m == 0) ? QSCALE : 1.0f;
    #pragma unroll
    for (int p = 0; p < 4; ++p) {
        int fi = tid + p * 256, r = fi >> 4, c4 = (fi & 15) * 4;
        *(float4*)&sh[r][c4] = *(const float4*)(Wsrc + r * 64 + c4);
    }
    __syncthreads();
    const int dout = tid >> 2, ks = (tid & 3) * 16;
    union { _Float16 h_[8]; float4 f; } pk;
    #pragma unroll
    for (int g = 0; g < 2; ++g) {
        #pragma unroll
        for (int j = 0; j < 8; ++j) pk.h_[j] = (_Float16)(sh[ks + 8 * g + j][dout] * scale);
        *(float4*)(Wt + ((long)((m * 12 + h) * 64 + dout)) * 64 + ks + 8 * g) = pk.f;
    }
}

// ---------------------------------------------------------------------------
// Prep B: W_last -> fp16 transposed Wt[n][k].
// ---------------------------------------------------------------------------
__global__ __launch_bounds__(256) void wt_kernel(
    const float* __restrict__ Wl, _Float16* __restrict__ Wt)
{
    __shared__ float sh[64][65];
    const int tid = threadIdx.x;
    const int k0 = blockIdx.x * 64, n0 = blockIdx.y * 64;
    #pragma unroll
    for (int p = 0; p < 4; ++p) {
        int fi = tid + p * 256, kk = fi >> 4, c4 = (fi & 15) * 4;
        *(float4*)&sh[kk][c4] = *(const float4*)(Wl + (long)(k0 + kk) * ND + n0 + c4);
    }
    __syncthreads();
    const int nn = tid >> 2, ks = (tid & 3) * 16;
    union { _Float16 h_[8]; float4 f; } pk;
    #pragma unroll
    for (int g = 0; g < 2; ++g) {
        #pragma unroll
        for (int j = 0; j < 8; ++j) pk.h_[j] = (_Float16)sh[ks + 8 * g + j][nn];
        *(float4*)(Wt + (long)(n0 + nn) * ND + k0 + ks + 8 * g) = pk.f;
    }
}

// ---------------------------------------------------------------------------
// Kernel 1: QKV projection, fp16 MFMA, D = W^T.X^T orientation.
// grid (128 tok-tiles, 12 h), 256 thr. D[m=dout][n=token]: lane holds 4
// contiguous dout per token -> half4 Q/K stores. V bounced through LDS
// (reusing Xs) -> coalesced half8 [d][s] stores. Bias folded into acc init.
// ---------------------------------------------------------------------------
__global__ __launch_bounds__(256) void qkv_kernel(
    const float* __restrict__ seq, const _Float16* __restrict__ Wt,
    const float* __restrict__ bq, const float* __restrict__ bk, const float* __restrict__ bv,
    _Float16* __restrict__ Qo, _Float16* __restrict__ Ko, _Float16* __restrict__ Vo)
{
    __shared__ _Float16 Xs[128][LDH];      // 18.4 KB, reused as V bounce
    __shared__ _Float16 Ws[3][64][LDH];    // 27.6 KB
    const int tid = threadIdx.x, w = tid >> 6, lane = tid & 63;
    const int quad = lane >> 4, lx = lane & 15;
    const int bx = blockIdx.x, h = blockIdx.y;
    const long tok0 = (long)bx * 128;
    const int b = bx >> 3, s0 = (bx & 7) * 128;
    const long hb = (long)b * NH + h;

    // stage X (fp32 -> fp16): 128 rows x 64 halves
    #pragma unroll
    for (int p = 0; p < 4; ++p) {
        int fi = tid + p * 256, r = fi >> 3, c8 = (fi & 7) * 8;
        const float* src = seq + (tok0 + r) * ND + h * NDH + c8;
        float4 f0 = *(const float4*)src, f1 = *(const float4*)(src + 4);
        union { _Float16 h_[8]; float4 f; } pk;
        pk.h_[0] = (_Float16)f0.x; pk.h_[1] = (_Float16)f0.y;
        pk.h_[2] = (_Float16)f0.z; pk.h_[3] = (_Float16)f0.w;
        pk.h_[4] = (_Float16)f1.x; pk.h_[5] = (_Float16)f1.y;
        pk.h_[6] = (_Float16)f1.z; pk.h_[7] = (_Float16)f1.w;
        *(float4*)&Xs[r][c8] = pk.f;
    }
    // stage W: 3 x 64 x 64 halves
    #pragma unroll
    for (int p = 0; p < 6; ++p) {
        int fi = tid + p * 256, m = fi >> 9, r = (fi >> 3) & 63, c8 = (fi & 7) * 8;
        *(float4*)&Ws[m][r][c8] = *(const float4*)(Wt + ((long)((m * 12 + h) * 64 + r)) * 64 + c8);
    }
    __syncthreads();

    // X B-frags: wave w owns token-tiles {2w, 2w+1}
    half8 xb[2][2];
    #pragma unroll
    for (int nt = 0; nt < 2; ++nt)
        #pragma unroll
        for (int kk = 0; kk < 2; ++kk)
            xb[nt][kk] = *(const half8*)&Xs[16 * (2 * w + nt) + lx][8 * quad + 32 * kk];

    const float* biases[3] = {bq, bk, bv};
    #pragma unroll
    for (int m = 0; m < 3; ++m) {
        half8 wa[4][2];
        #pragma unroll
        for (int mt = 0; mt < 4; ++mt)
            #pragma unroll
            for (int kk = 0; kk < 2; ++kk)
                wa[mt][kk] = *(const half8*)&Ws[m][16 * mt + lx][8 * quad + 32 * kk];

        const float bsc = (m == 0) ? QSCALE : 1.0f;
        floatx4 acc[4][2];
        #pragma unroll
        for (int mt = 0; mt < 4; ++mt) {
            float4 b4 = *(const float4*)&biases[m][h * NDH + 16 * mt + 4 * quad];
            floatx4 bi; bi[0] = b4.x * bsc; bi[1] = b4.y * bsc; bi[2] = b4.z * bsc; bi[3] = b4.w * bsc;
            #pragma unroll
            for (int nt = 0; nt < 2; ++nt) acc[mt][nt] = bi;
        }
        #pragma unroll
        for (int kk = 0; kk < 2; ++kk)
            #pragma unroll
            for (int mt = 0; mt < 4; ++mt)
                #pragma unroll
                for (int nt = 0; nt < 2; ++nt)
                    acc[mt][nt] = __builtin_amdgcn_mfma_f32_16x16x32_f16(wa[mt][kk], xb[nt][kk], acc[mt][nt], 0, 0, 0);

        if (m < 2) {
            _Float16* Out = (m == 0) ? Qo : Ko;
            #pragma unroll
            for (int nt = 0; nt < 2; ++nt) {
                const long token = s0 + 16 * (2 * w + nt) + lx;
                #pragma unroll
                for (int mt = 0; mt < 4; ++mt) {
                    half4 pk;
                    #pragma unroll
                    for (int p = 0; p < 4; ++p) pk[p] = (_Float16)acc[mt][nt][p];
                    *(half4*)&Out[(hb * NS + token) * NDH + 16 * mt + 4 * quad] = pk;
                }
            }
        } else {
            // V: bounce through LDS (reuse Xs) to get coalesced [d][s] stores
            __syncthreads();
            _Float16 (*Vb)[136] = (_Float16(*)[136])&Xs[0][0];
            #pragma unroll
            for (int nt = 0; nt < 2; ++nt) {
                const int tok = 16 * (2 * w + nt) + lx;
                #pragma unroll
                for (int mt = 0; mt < 4; ++mt)
                    #pragma unroll
                    for (int p = 0; p < 4; ++p)
                        Vb[16 * mt + 4 * quad + p][tok] = (_Float16)acc[mt][nt][p];
            }
            __syncthreads();
            #pragma unroll
            for (int p = 0; p < 4; ++p) {
                int fi = tid + p * 256, r = fi >> 4, c8 = (fi & 15) * 8;
                *(float4*)(Vo + (hb * NDH + r) * NS + s0 + c8) = *(float4*)&Vb[r][c8];
            }
        }
    }
}

// ---------------------------------------------------------------------------
// Kernel 2: flash attention. grid = 1536 (XCD-swizzled), 256 thr = 4 waves.
// LDS = K/V tiles only (18.4KB) -> 6 blocks/CU co-resident. Q B-frags loaded
// directly from global (loop-invariant). S^T = K.Q^T; P stays in registers;
// PV computed as O^T = mfma(A=V^T-frag, B=P-frag) -> half4 output stores.
// ---------------------------------------------------------------------------
__global__ __launch_bounds__(256, 8) void attn_kernel(
    const _Float16* __restrict__ Q, const _Float16* __restrict__ K,
    const _Float16* __restrict__ Vt, _Float16* __restrict__ O)
{
    __shared__ _Float16 Ks[64][LDH];    // 9.2 KB
    __shared__ _Float16 Vs[64][LDH];    // 9.2 KB  (Vs[d][k])

    const int tid = threadIdx.x, w = tid >> 6, lane = tid & 63;
    const int quad = lane >> 4, lx = lane & 15;
    const int flat = blockIdx.x;
    const int xcd = flat & 7, rest = flat >> 3;
    const int qb = rest & 7, bhg = rest >> 3;
    const int bh = bhg * 8 + xcd;
    const int bb = bh / NH, h = bh % NH;
    const int q0 = qb * 128;
    const long hb = bh;

    // Q B-frags direct from global (one-time; L2/L3-resident)
    half8 bq[2][2];
    #pragma unroll
    for (int qb2 = 0; qb2 < 2; ++qb2)
        #pragma unroll
        for (int kk = 0; kk < 2; ++kk)
            bq[qb2][kk] = *(const half8*)(Q + (hb * NS + q0 + 32 * w + 16 * qb2 + lx) * NDH + 8 * quad + 32 * kk);

    float l_acc[2] = {0.f, 0.f};
    floatx4 o_acc[2][4];
    #pragma unroll
    for (int qb2 = 0; qb2 < 2; ++qb2)
        #pragma unroll
        for (int nt = 0; nt < 4; ++nt) o_acc[qb2][nt] = (floatx4)0.f;

    for (int kt = 0; kt < NS / 64; ++kt) {
        __syncthreads();
        #pragma unroll
        for (int p = 0; p < 2; ++p) {
            int fi = tid + p * 256, r = fi >> 3, c8 = (fi & 7) * 8;
            *(float4*)&Ks[r][c8] = *(const float4*)(K  + (hb * NS + kt * 64 + r) * NDH + c8);
            *(float4*)&Vs[r][c8] = *(const float4*)(Vt + (hb * NDH + r) * NS + kt * 64 + c8);
        }
        __syncthreads();

        // K A-frags (shared by both q-sub-tiles)
        half8 ak[4][2];
        #pragma unroll
        for (int jt = 0; jt < 4; ++jt)
            #pragma unroll
            for (int kk = 0; kk < 2; ++kk)
                ak[jt][kk] = *(const half8*)&Ks[16 * jt + lx][8 * quad + 32 * kk];

        // S^T = K.Q^T, then P = exp2(S^T) in-register
        half4 af[2][4];
        #pragma unroll
        for (int qb2 = 0; qb2 < 2; ++qb2) {
            #pragma unroll
            for (int jt = 0; jt < 4; ++jt) {
                floatx4 st = (floatx4)0.f;
                st = __builtin_amdgcn_mfma_f32_16x16x32_f16(ak[jt][0], bq[qb2][0], st, 0, 0, 0);
                st = __builtin_amdgcn_mfma_f32_16x16x32_f16(ak[jt][1], bq[qb2][1], st, 0, 0, 0);
                float e0 = __builtin_amdgcn_exp2f(st[0]);
                float e1 = __builtin_amdgcn_exp2f(st[1]);
                float e2 = __builtin_amdgcn_exp2f(st[2]);
                float e3 = __builtin_amdgcn_exp2f(st[3]);
                l_acc[qb2] += (e0 + e1) + (e2 + e3);
                half4 pf;
                pf[0] = (_Float16)e0; pf[1] = (_Float16)e1;
                pf[2] = (_Float16)e2; pf[3] = (_Float16)e3;
                af[qb2][jt] = pf;
            }
        }

        // O^T[d][q] += V^T[d][k] . P^T[k][q]  (A=V^T frag, B=P frag == af)
        #pragma unroll
        for (int nt = 0; nt < 4; ++nt) {
            half4 vf[4];
            #pragma unroll
            for (int jt = 0; jt < 4; ++jt)
                vf[jt] = *(const half4*)&Vs[16 * nt + lx][16 * jt + 4 * quad];
            #pragma unroll
            for (int qb2 = 0; qb2 < 2; ++qb2)
                #pragma unroll
                for (int jt = 0; jt < 4; ++jt)
                    o_acc[qb2][nt] = __builtin_amdgcn_mfma_f32_16x16x16f16(vf[jt], af[qb2][jt], o_acc[qb2][nt], 0, 0, 0);
        }
    }

    // epilogue: reduce l across quads (lanes sharing lx), normalize, half4 stores
    #pragma unroll
    for (int qb2 = 0; qb2 < 2; ++qb2) {
        float l = l_acc[qb2];
        l += __shfl_xor(l, 16);
        l += __shfl_xor(l, 32);
        const float inv = 1.f / l;
        const long row = (long)bb * NS + q0 + 32 * w + 16 * qb2 + lx;
        #pragma unroll
        for (int nt = 0; nt < 4; ++nt) {
            half4 pk;
            #pragma unroll
            for (int p = 0; p < 4; ++p) pk[p] = (_Float16)(o_acc[qb2][nt][p] * inv);
            *(half4*)(O + row * ND + h * NDH + 16 * nt + 4 * quad) = pk;
        }
    }
}

// ---------------------------------------------------------------------------
// Kernel 3: output projection, fp16 MFMA, 128x128 tile. (unchanged)
// ---------------------------------------------------------------------------
__global__ __launch_bounds__(256) void out_proj_kernel(
    const _Float16* __restrict__ X, const _Float16* __restrict__ Wt,
    const float* __restrict__ bl, float* __restrict__ out)
{
    __shared__ _Float16 Ah[128][LDH];
    __shared__ _Float16 Bh[128][LDH];

    const int tid = threadIdx.x, w = tid >> 6, lane = tid & 63;
    const int quad = lane >> 4, lx = lane & 15;
    const int wm = (w >> 1) * 64, wn = (w & 1) * 64;
    const long r0 = (long)blockIdx.x * 128;
    const int c0 = blockIdx.y * 128;

    floatx4 acc[4][4];
    #pragma unroll
    for (int mt = 0; mt < 4; ++mt)
        #pragma unroll
        for (int nt = 0; nt < 4; ++nt) acc[mt][nt] = (floatx4)0.f;

    for (int kt = 0; kt < ND / 64; ++kt) {
        __syncthreads();
        #pragma unroll
        for (int p = 0; p < 4; ++p) {
            int fi = tid + p * 256, r = fi >> 3, c8 = (fi & 7) * 8;
            *(float4*)&Ah[r][c8] = *(const float4*)(X  + (r0 + r) * ND + kt * 64 + c8);
            *(float4*)&Bh[r][c8] = *(const float4*)(Wt + (long)(c0 + r) * ND + kt * 64 + c8);
        }
        __syncthreads();

        #pragma unroll
        for (int kk = 0; kk < 2; ++kk) {
            half8 a[4], b[4];
            #pragma unroll
            for (int mt = 0; mt < 4; ++mt)
                a[mt] = *(const half8*)&Ah[wm + 16 * mt + lx][kk * 32 + quad * 8];
            #pragma unroll
            for (int nt = 0; nt < 4; ++nt)
                b[nt] = *(const half8*)&Bh[wn + 16 * nt + lx][kk * 32 + quad * 8];
            #pragma unroll
            for (int mt = 0; mt < 4; ++mt)
                #pragma unroll
                for (int nt = 0; nt < 4; ++nt)
                    acc[mt][nt] = __builtin_amdgcn_mfma_f32_16x16x32_f16(a[mt], b[nt], acc[mt][nt], 0, 0, 0);
        }
    }

    #pragma unroll
    for (int mt = 0; mt < 4; ++mt)
        #pragma unroll
        for (int nt = 0; nt < 4; ++nt) {
            const int col = c0 + wn + 16 * nt + lx;
            const float bv = bl[col];
            #pragma unroll
            for (int p = 0; p < 4; ++p) {
                const long row = r0 + wm + 16 * mt + quad * 4 + p;
                out[row * ND + col] = acc[mt][nt][p] + bv;
            }
        }
}

// ---------------------------------------------------------------------------
extern "C" void kernel_launch(void* const* d_in, const int* in_sizes, int n_in,
                              void* d_out, int out_size, void* d_ws, size_t ws_size,
                              hipStream_t stream) {
    const float* seq    = (const float*)d_in[0];
    const float* Wq     = (const float*)d_in[1];
    const float* bq     = (const float*)d_in[2];
    const float* Wk     = (const float*)d_in[3];
    const float* bk     = (const float*)d_in[4];
    const float* Wv     = (const float*)d_in[5];
    const float* bv     = (const float*)d_in[6];
    const float* W_last = (const float*)d_in[7];
    const float* b_last = (const float*)d_in[8];
    float* out = (float*)d_out;

    const long HN = (long)NB * NH * NS * NDH;   // 12,582,912
    _Float16* qh   = (_Float16*)d_ws;
    _Float16* kh   = qh + HN;
    _Float16* vt   = kh + HN;
    _Float16* xh   = vt + HN;
    _Float16* wtL  = xh + (long)NB * NS * ND;
    _Float16* wtQKV = wtL + (long)ND * ND;

    wqkv_prep<<<dim3(3, NH), 256, 0, stream>>>(Wq, Wk, Wv, wtQKV);
    wt_kernel<<<dim3(ND / 64, ND / 64), 256, 0, stream>>>(W_last, wtL);
    qkv_kernel<<<dim3(NB * NS / 128, NH), 256, 0, stream>>>(seq, wtQKV, bq, bk, bv, qh, kh, vt);
    attn_kernel<<<NB * NH * (NS / 128), 256, 0, stream>>>(qh, kh, vt, xh);
    out_proj_kernel<<<dim3(NB * NS / 128, ND / 128), 256, 0, stream>>>(xh, wtL, b_last, out);
}

// Round 7
// 237.321 us; speedup vs baseline: 2.9704x; 2.9704x over previous
//
#include <hip/hip_runtime.h>

// MultiHeadSelfAttention: B=16, S=1024, D=768, H=12, DH=64, fp32 in/out.
// R6 = R5 with the register cliff fixed: __launch_bounds__(256,4) on attn
// (256,8 forced VGPR=32 -> full scratch spill -> 1GB+ HBM traffic, 5.8% MfmaUtil).
// Kernel needs ~116 VGPRs; 4 waves/EU (cap 128) is the max safe bound.

#define NB 16
#define NS 1024
#define ND 768
#define NH 12
#define NDH 64
#define LDH 72        // LDS row stride in halves (144B)
#define QSCALE 0.18033688f   // 0.125 * log2(e)

typedef _Float16 half8 __attribute__((ext_vector_type(8)));
typedef _Float16 half4 __attribute__((ext_vector_type(4)));
typedef float floatx4 __attribute__((ext_vector_type(4)));

// ---------------------------------------------------------------------------
// Prep A: per-head W q/k/v -> fp16, transposed to [m][h][dout][din]; Wq scaled.
// ---------------------------------------------------------------------------
__global__ __launch_bounds__(256) void wqkv_prep(
    const float* __restrict__ Wq, const float* __restrict__ Wk,
    const float* __restrict__ Wv, _Float16* __restrict__ Wt)
{
    __shared__ float sh[64][65];
    const int m = blockIdx.x, h = blockIdx.y, tid = threadIdx.x;
    const float* Wsrc = (m == 0 ? Wq : (m == 1 ? Wk : Wv)) + h * 4096;
    const float scale = (m == 0) ? QSCALE : 1.0f;
    #pragma unroll
    for (int p = 0; p < 4; ++p) {
        int fi = tid + p * 256, r = fi >> 4, c4 = (fi & 15) * 4;
        *(float4*)&sh[r][c4] = *(const float4*)(Wsrc + r * 64 + c4);
    }
    __syncthreads();
    const int dout = tid >> 2, ks = (tid & 3) * 16;
    union { _Float16 h_[8]; float4 f; } pk;
    #pragma unroll
    for (int g = 0; g < 2; ++g) {
        #pragma unroll
        for (int j = 0; j < 8; ++j) pk.h_[j] = (_Float16)(sh[ks + 8 * g + j][dout] * scale);
        *(float4*)(Wt + ((long)((m * 12 + h) * 64 + dout)) * 64 + ks + 8 * g) = pk.f;
    }
}

// ---------------------------------------------------------------------------
// Prep B: W_last -> fp16 transposed Wt[n][k].
// ---------------------------------------------------------------------------
__global__ __launch_bounds__(256) void wt_kernel(
    const float* __restrict__ Wl, _Float16* __restrict__ Wt)
{
    __shared__ float sh[64][65];
    const int tid = threadIdx.x;
    const int k0 = blockIdx.x * 64, n0 = blockIdx.y * 64;
    #pragma unroll
    for (int p = 0; p < 4; ++p) {
        int fi = tid + p * 256, kk = fi >> 4, c4 = (fi & 15) * 4;
        *(float4*)&sh[kk][c4] = *(const float4*)(Wl + (long)(k0 + kk) * ND + n0 + c4);
    }
    __syncthreads();
    const int nn = tid >> 2, ks = (tid & 3) * 16;
    union { _Float16 h_[8]; float4 f; } pk;
    #pragma unroll
    for (int g = 0; g < 2; ++g) {
        #pragma unroll
        for (int j = 0; j < 8; ++j) pk.h_[j] = (_Float16)sh[ks + 8 * g + j][nn];
        *(float4*)(Wt + (long)(n0 + nn) * ND + k0 + ks + 8 * g) = pk.f;
    }
}

// ---------------------------------------------------------------------------
// Kernel 1: QKV projection, fp16 MFMA, D = W^T.X^T orientation.
// grid (128 tok-tiles, 12 h), 256 thr. D[m=dout][n=token]: lane holds 4
// contiguous dout per token -> half4 Q/K stores. V bounced through LDS
// (reusing Xs) -> coalesced half8 [d][s] stores. Bias folded into acc init.
// ---------------------------------------------------------------------------
__global__ __launch_bounds__(256) void qkv_kernel(
    const float* __restrict__ seq, const _Float16* __restrict__ Wt,
    const float* __restrict__ bq, const float* __restrict__ bk, const float* __restrict__ bv,
    _Float16* __restrict__ Qo, _Float16* __restrict__ Ko, _Float16* __restrict__ Vo)
{
    __shared__ _Float16 Xs[128][LDH];      // 18.4 KB, reused as V bounce
    __shared__ _Float16 Ws[3][64][LDH];    // 27.6 KB
    const int tid = threadIdx.x, w = tid >> 6, lane = tid & 63;
    const int quad = lane >> 4, lx = lane & 15;
    const int bx = blockIdx.x, h = blockIdx.y;
    const long tok0 = (long)bx * 128;
    const int b = bx >> 3, s0 = (bx & 7) * 128;
    const long hb = (long)b * NH + h;

    // stage X (fp32 -> fp16): 128 rows x 64 halves
    #pragma unroll
    for (int p = 0; p < 4; ++p) {
        int fi = tid + p * 256, r = fi >> 3, c8 = (fi & 7) * 8;
        const float* src = seq + (tok0 + r) * ND + h * NDH + c8;
        float4 f0 = *(const float4*)src, f1 = *(const float4*)(src + 4);
        union { _Float16 h_[8]; float4 f; } pk;
        pk.h_[0] = (_Float16)f0.x; pk.h_[1] = (_Float16)f0.y;
        pk.h_[2] = (_Float16)f0.z; pk.h_[3] = (_Float16)f0.w;
        pk.h_[4] = (_Float16)f1.x; pk.h_[5] = (_Float16)f1.y;
        pk.h_[6] = (_Float16)f1.z; pk.h_[7] = (_Float16)f1.w;
        *(float4*)&Xs[r][c8] = pk.f;
    }
    // stage W: 3 x 64 x 64 halves
    #pragma unroll
    for (int p = 0; p < 6; ++p) {
        int fi = tid + p * 256, m = fi >> 9, r = (fi >> 3) & 63, c8 = (fi & 7) * 8;
        *(float4*)&Ws[m][r][c8] = *(const float4*)(Wt + ((long)((m * 12 + h) * 64 + r)) * 64 + c8);
    }
    __syncthreads();

    // X B-frags: wave w owns token-tiles {2w, 2w+1}
    half8 xb[2][2];
    #pragma unroll
    for (int nt = 0; nt < 2; ++nt)
        #pragma unroll
        for (int kk = 0; kk < 2; ++kk)
            xb[nt][kk] = *(const half8*)&Xs[16 * (2 * w + nt) + lx][8 * quad + 32 * kk];

    const float* biases[3] = {bq, bk, bv};
    #pragma unroll
    for (int m = 0; m < 3; ++m) {
        half8 wa[4][2];
        #pragma unroll
        for (int mt = 0; mt < 4; ++mt)
            #pragma unroll
            for (int kk = 0; kk < 2; ++kk)
                wa[mt][kk] = *(const half8*)&Ws[m][16 * mt + lx][8 * quad + 32 * kk];

        const float bsc = (m == 0) ? QSCALE : 1.0f;
        floatx4 acc[4][2];
        #pragma unroll
        for (int mt = 0; mt < 4; ++mt) {
            float4 b4 = *(const float4*)&biases[m][h * NDH + 16 * mt + 4 * quad];
            floatx4 bi; bi[0] = b4.x * bsc; bi[1] = b4.y * bsc; bi[2] = b4.z * bsc; bi[3] = b4.w * bsc;
            #pragma unroll
            for (int nt = 0; nt < 2; ++nt) acc[mt][nt] = bi;
        }
        #pragma unroll
        for (int kk = 0; kk < 2; ++kk)
            #pragma unroll
            for (int mt = 0; mt < 4; ++mt)
                #pragma unroll
                for (int nt = 0; nt < 2; ++nt)
                    acc[mt][nt] = __builtin_amdgcn_mfma_f32_16x16x32_f16(wa[mt][kk], xb[nt][kk], acc[mt][nt], 0, 0, 0);

        if (m < 2) {
            _Float16* Out = (m == 0) ? Qo : Ko;
            #pragma unroll
            for (int nt = 0; nt < 2; ++nt) {
                const long token = s0 + 16 * (2 * w + nt) + lx;
                #pragma unroll
                for (int mt = 0; mt < 4; ++mt) {
                    half4 pk;
                    #pragma unroll
                    for (int p = 0; p < 4; ++p) pk[p] = (_Float16)acc[mt][nt][p];
                    *(half4*)&Out[(hb * NS + token) * NDH + 16 * mt + 4 * quad] = pk;
                }
            }
        } else {
            // V: bounce through LDS (reuse Xs) to get coalesced [d][s] stores
            __syncthreads();
            _Float16 (*Vb)[136] = (_Float16(*)[136])&Xs[0][0];
            #pragma unroll
            for (int nt = 0; nt < 2; ++nt) {
                const int tok = 16 * (2 * w + nt) + lx;
                #pragma unroll
                for (int mt = 0; mt < 4; ++mt)
                    #pragma unroll
                    for (int p = 0; p < 4; ++p)
                        Vb[16 * mt + 4 * quad + p][tok] = (_Float16)acc[mt][nt][p];
            }
            __syncthreads();
            #pragma unroll
            for (int p = 0; p < 4; ++p) {
                int fi = tid + p * 256, r = fi >> 4, c8 = (fi & 15) * 8;
                *(float4*)(Vo + (hb * NDH + r) * NS + s0 + c8) = *(float4*)&Vb[r][c8];
            }
        }
    }
}

// ---------------------------------------------------------------------------
// Kernel 2: flash attention. grid = 1536 (XCD-swizzled), 256 thr = 4 waves.
// LDS = K/V tiles only (18.4KB). Q B-frags direct from global (loop-invariant).
// S^T = K.Q^T; P stays in registers; O^T = mfma(A=V^T-frag, B=P-frag).
// __launch_bounds__(256,4): kernel needs ~116 VGPRs; cap 128, no spill.
// ---------------------------------------------------------------------------
__global__ __launch_bounds__(256, 4) void attn_kernel(
    const _Float16* __restrict__ Q, const _Float16* __restrict__ K,
    const _Float16* __restrict__ Vt, _Float16* __restrict__ O)
{
    __shared__ _Float16 Ks[64][LDH];    // 9.2 KB
    __shared__ _Float16 Vs[64][LDH];    // 9.2 KB  (Vs[d][k])

    const int tid = threadIdx.x, w = tid >> 6, lane = tid & 63;
    const int quad = lane >> 4, lx = lane & 15;
    const int flat = blockIdx.x;
    const int xcd = flat & 7, rest = flat >> 3;
    const int qb = rest & 7, bhg = rest >> 3;
    const int bh = bhg * 8 + xcd;
    const int bb = bh / NH, h = bh % NH;
    const int q0 = qb * 128;
    const long hb = bh;

    // Q B-frags direct from global (one-time; L2/L3-resident)
    half8 bq[2][2];
    #pragma unroll
    for (int qb2 = 0; qb2 < 2; ++qb2)
        #pragma unroll
        for (int kk = 0; kk < 2; ++kk)
            bq[qb2][kk] = *(const half8*)(Q + (hb * NS + q0 + 32 * w + 16 * qb2 + lx) * NDH + 8 * quad + 32 * kk);

    float l_acc[2] = {0.f, 0.f};
    floatx4 o_acc[2][4];
    #pragma unroll
    for (int qb2 = 0; qb2 < 2; ++qb2)
        #pragma unroll
        for (int nt = 0; nt < 4; ++nt) o_acc[qb2][nt] = (floatx4)0.f;

    for (int kt = 0; kt < NS / 64; ++kt) {
        __syncthreads();
        #pragma unroll
        for (int p = 0; p < 2; ++p) {
            int fi = tid + p * 256, r = fi >> 3, c8 = (fi & 7) * 8;
            *(float4*)&Ks[r][c8] = *(const float4*)(K  + (hb * NS + kt * 64 + r) * NDH + c8);
            *(float4*)&Vs[r][c8] = *(const float4*)(Vt + (hb * NDH + r) * NS + kt * 64 + c8);
        }
        __syncthreads();

        // K A-frags (shared by both q-sub-tiles)
        half8 ak[4][2];
        #pragma unroll
        for (int jt = 0; jt < 4; ++jt)
            #pragma unroll
            for (int kk = 0; kk < 2; ++kk)
                ak[jt][kk] = *(const half8*)&Ks[16 * jt + lx][8 * quad + 32 * kk];

        // S^T = K.Q^T, then P = exp2(S^T) in-register
        half4 af[2][4];
        #pragma unroll
        for (int qb2 = 0; qb2 < 2; ++qb2) {
            #pragma unroll
            for (int jt = 0; jt < 4; ++jt) {
                floatx4 st = (floatx4)0.f;
                st = __builtin_amdgcn_mfma_f32_16x16x32_f16(ak[jt][0], bq[qb2][0], st, 0, 0, 0);
                st = __builtin_amdgcn_mfma_f32_16x16x32_f16(ak[jt][1], bq[qb2][1], st, 0, 0, 0);
                float e0 = __builtin_amdgcn_exp2f(st[0]);
                float e1 = __builtin_amdgcn_exp2f(st[1]);
                float e2 = __builtin_amdgcn_exp2f(st[2]);
                float e3 = __builtin_amdgcn_exp2f(st[3]);
                l_acc[qb2] += (e0 + e1) + (e2 + e3);
                half4 pf;
                pf[0] = (_Float16)e0; pf[1] = (_Float16)e1;
                pf[2] = (_Float16)e2; pf[3] = (_Float16)e3;
                af[qb2][jt] = pf;
            }
        }

        // O^T[d][q] += V^T[d][k] . P^T[k][q]  (A=V^T frag, B=P frag == af)
        #pragma unroll
        for (int nt = 0; nt < 4; ++nt) {
            half4 vf[4];
            #pragma unroll
            for (int jt = 0; jt < 4; ++jt)
                vf[jt] = *(const half4*)&Vs[16 * nt + lx][16 * jt + 4 * quad];
            #pragma unroll
            for (int qb2 = 0; qb2 < 2; ++qb2)
                #pragma unroll
                for (int jt = 0; jt < 4; ++jt)
                    o_acc[qb2][nt] = __builtin_amdgcn_mfma_f32_16x16x16f16(vf[jt], af[qb2][jt], o_acc[qb2][nt], 0, 0, 0);
        }
    }

    // epilogue: reduce l across quads (lanes sharing lx), normalize, half4 stores
    #pragma unroll
    for (int qb2 = 0; qb2 < 2; ++qb2) {
        float l = l_acc[qb2];
        l += __shfl_xor(l, 16);
        l += __shfl_xor(l, 32);
        const float inv = 1.f / l;
        const long row = (long)bb * NS + q0 + 32 * w + 16 * qb2 + lx;
        #pragma unroll
        for (int nt = 0; nt < 4; ++nt) {
            half4 pk;
            #pragma unroll
            for (int p = 0; p < 4; ++p) pk[p] = (_Float16)(o_acc[qb2][nt][p] * inv);
            *(half4*)(O + row * ND + h * NDH + 16 * nt + 4 * quad) = pk;
        }
    }
}

// ---------------------------------------------------------------------------
// Kernel 3: output projection, fp16 MFMA, 128x128 tile. (unchanged)
// ---------------------------------------------------------------------------
__global__ __launch_bounds__(256) void out_proj_kernel(
    const _Float16* __restrict__ X, const _Float16* __restrict__ Wt,
    const float* __restrict__ bl, float* __restrict__ out)
{
    __shared__ _Float16 Ah[128][LDH];
    __shared__ _Float16 Bh[128][LDH];

    const int tid = threadIdx.x, w = tid >> 6, lane = tid & 63;
    const int quad = lane >> 4, lx = lane & 15;
    const int wm = (w >> 1) * 64, wn = (w & 1) * 64;
    const long r0 = (long)blockIdx.x * 128;
    const int c0 = blockIdx.y * 128;

    floatx4 acc[4][4];
    #pragma unroll
    for (int mt = 0; mt < 4; ++mt)
        #pragma unroll
        for (int nt = 0; nt < 4; ++nt) acc[mt][nt] = (floatx4)0.f;

    for (int kt = 0; kt < ND / 64; ++kt) {
        __syncthreads();
        #pragma unroll
        for (int p = 0; p < 4; ++p) {
            int fi = tid + p * 256, r = fi >> 3, c8 = (fi & 7) * 8;
            *(float4*)&Ah[r][c8] = *(const float4*)(X  + (r0 + r) * ND + kt * 64 + c8);
            *(float4*)&Bh[r][c8] = *(const float4*)(Wt + (long)(c0 + r) * ND + kt * 64 + c8);
        }
        __syncthreads();

        #pragma unroll
        for (int kk = 0; kk < 2; ++kk) {
            half8 a[4], b[4];
            #pragma unroll
            for (int mt = 0; mt < 4; ++mt)
                a[mt] = *(const half8*)&Ah[wm + 16 * mt + lx][kk * 32 + quad * 8];
            #pragma unroll
            for (int nt = 0; nt < 4; ++nt)
                b[nt] = *(const half8*)&Bh[wn + 16 * nt + lx][kk * 32 + quad * 8];
            #pragma unroll
            for (int mt = 0; mt < 4; ++mt)
                #pragma unroll
                for (int nt = 0; nt < 4; ++nt)
                    acc[mt][nt] = __builtin_amdgcn_mfma_f32_16x16x32_f16(a[mt], b[nt], acc[mt][nt], 0, 0, 0);
        }
    }

    #pragma unroll
    for (int mt = 0; mt < 4; ++mt)
        #pragma unroll
        for (int nt = 0; nt < 4; ++nt) {
            const int col = c0 + wn + 16 * nt + lx;
            const float bv = bl[col];
            #pragma unroll
            for (int p = 0; p < 4; ++p) {
                const long row = r0 + wm + 16 * mt + quad * 4 + p;
                out[row * ND + col] = acc[mt][nt][p] + bv;
            }
        }
}

// ---------------------------------------------------------------------------
extern "C" void kernel_launch(void* const* d_in, const int* in_sizes, int n_in,
                              void* d_out, int out_size, void* d_ws, size_t ws_size,
                              hipStream_t stream) {
    const float* seq    = (const float*)d_in[0];
    const float* Wq     = (const float*)d_in[1];
    const float* bq     = (const float*)d_in[2];
    const float* Wk     = (const float*)d_in[3];
    const float* bk     = (const float*)d_in[4];
    const float* Wv     = (const float*)d_in[5];
    const float* bv     = (const float*)d_in[6];
    const float* W_last = (const float*)d_in[7];
    const float* b_last = (const float*)d_in[8];
    float* out = (float*)d_out;

    const long HN = (long)NB * NH * NS * NDH;   // 12,582,912
    _Float16* qh   = (_Float16*)d_ws;
    _Float16* kh   = qh + HN;
    _Float16* vt   = kh + HN;
    _Float16* xh   = vt + HN;
    _Float16* wtL  = xh + (long)NB * NS * ND;
    _Float16* wtQKV = wtL + (long)ND * ND;

    wqkv_prep<<<dim3(3, NH), 256, 0, stream>>>(Wq, Wk, Wv, wtQKV);
    wt_kernel<<<dim3(ND / 64, ND / 64), 256, 0, stream>>>(W_last, wtL);
    qkv_kernel<<<dim3(NB * NS / 128, NH), 256, 0, stream>>>(seq, wtQKV, bq, bk, bv, qh, kh, vt);
    attn_kernel<<<NB * NH * (NS / 128), 256, 0, stream>>>(qh, kh, vt, xh);
    out_proj_kernel<<<dim3(NB * NS / 128, ND / 128), 256, 0, stream>>>(xh, wtL, b_last, out);
}